// Round 5
// baseline (160.882 us; speedup 1.0000x reference)
//
#include <hip/hip_runtime.h>

#define NB 8
#define N1 2048
#define N2 1152
#define KD 1024
#define BM 256
#define BN 144
#define BNP 145     // padded epilogue stride
#define BUFB 25600  // one staging buffer: 25 chunks x 1 KB (16 A + 9 B)
#define NBUF 3      // triple buffer -> counted vmcnt, no drain in loop (R3 +5us)

typedef __attribute__((ext_vector_type(4))) float f32x4;
typedef __attribute__((ext_vector_type(2))) long i64x2;

__device__ __forceinline__ unsigned pack4_fp8(f32x4 v) {
  int t = __builtin_amdgcn_cvt_pk_fp8_f32(v.x, v.y, 0, false);
  t = __builtin_amdgcn_cvt_pk_fp8_f32(v.z, v.w, t, true);
  return (unsigned)t;
}

__device__ __forceinline__ void async_copy16(const void* g, void* l) {
  __builtin_amdgcn_global_load_lds(
      (const __attribute__((address_space(1))) unsigned int*)g,
      (__attribute__((address_space(3))) unsigned int*)l, 16, 0, 0);
}

// convert: R4-verbatim (passed, absmax 0). ONE wave per row; wave-private LDS
// permute -> lgkmcnt(0) only, no block barrier. XCD-aligned: bid&7 = batch,
// fp8 writes stay hot in that XCD's 4 MB L2 for dist (R8-verified).
__global__ __launch_bounds__(256) void convert_kernel(
    const float* __restrict__ x1, const float* __restrict__ x2,
    unsigned char* __restrict__ x1q, unsigned char* __restrict__ x2q,
    float* __restrict__ sq1, float* __restrict__ sq2,
    float* __restrict__ out) {
  __shared__ __align__(16) unsigned char lds[4096];
  if (blockIdx.x == 0 && threadIdx.x == 0) *out = 0.f;  // replaces memset
  int wave = threadIdx.x >> 6, lane = threadIdx.x & 63;
  int bid = blockIdx.x;
  int b = bid & 7;          // batch -> XCD
  int idx = bid >> 3;       // 0..799 within batch
  const float* src;
  unsigned char* dst;
  float* sqp;
  if (idx < N1 / 4) {
    int row = b * N1 + idx * 4 + wave;
    src = x1 + (size_t)row * KD;
    dst = x1q + (size_t)row * KD;
    sqp = sq1 + row;
  } else {
    int row = b * N2 + (idx - N1 / 4) * 4 + wave;
    src = x2 + (size_t)row * KD;
    dst = x2q + (size_t)row * KD;
    sqp = sq2 + row;
  }
  const f32x4* s4 = (const f32x4*)src;
  int r = 4 * (lane & 15);
  int q = (r & 31) >> 3;
  int h = r >> 5;
  int pos = (lane >> 4) * 64 + q * 16 + h * 8 + (r & 7);
  unsigned char* my = lds + wave * 1024;
  float s = 0.f;
#pragma unroll
  for (int i = 0; i < 4; ++i) {
    f32x4 v = __builtin_nontemporal_load(&s4[i * 64 + lane]);
    *(unsigned*)(my + i * 256 + pos) = pack4_fp8(v);
    s += v.x * v.x + v.y * v.y + v.z * v.z + v.w * v.w;
  }
  // wave-private LDS, intra-wave lane exchange only: no block barrier needed
  asm volatile("s_waitcnt lgkmcnt(0)" ::: "memory");
  ((uint4*)dst)[lane] = *(const uint4*)(my + lane * 16);
#pragma unroll
  for (int off = 32; off > 0; off >>= 1) s += __shfl_down(s, off);
  if (lane == 0) *sqp = s;
}

// dist R14: 8-WAVE blocks (512 thr), same 256x144 tile, tribuf + counted
// vmcnt. Theory: at 4-wave blocks (2 waves/SIMD) the post-barrier ds_read
// head (~180cy) + barrier skew is exposed — matrix pipe starves. 8 waves x
// 2 blocks = 16 waves/CU (4/SIMD) doubles TLP; per-wave tile 32x144
// (acc[2][9]=72 regs, was 144 -> VGPR headroom). Same total LDS traffic.
// Staging UNIFORM 4 loads/wave: chunks 3w..3w+2 (w<8 covers 0..23) + chunk
// 24 by ALL waves redundantly (identical-value LDS writes, benign) ->
// vmcnt immediate wave-uniform. Tribuf accounting: prologue 2 stages = 8
// outstanding; per-iter vmcnt(4) drains EXACTLY stage(cur) (oldest 4,
// in-order completion). lgkmcnt(0)+vmcnt(4) BEFORE s_barrier => after
// barrier buf[cur] fully staged by all waves and buf[cur+2] (overwritten
// next) has no pending readers (R3-proven skeleton, absmax 0).
// CRITICAL (unchanged): every loop touching acc[][] FULLY UNROLLED — any
// runtime index scratches accumulators (tripwire: WRITE_SIZE stays ~0).
// Grid 512: b = bid&7 -> batch b on XCD b (fp8 L2-hot from convert).
// LDS chunks 1 KB = 16 rows x 64 fp8, XOR swizzle (slot ^ (row>>1)&3) ->
// conflict-free b128 fragment reads (verified R2-R9).
// LDS 3*25600 = 76800 B; epilogue needs 128*145*4 = 74240 <= 76800 OK.
// 2 blocks/CU: LDS 153.6K <= 160K, 16 waves <= 32.
__global__ __launch_bounds__(512, 4) void dist_kernel(
    const unsigned char* __restrict__ x1q, const unsigned char* __restrict__ x2q,
    const float* __restrict__ sq1, const float* __restrict__ sq2,
    float* __restrict__ out) {
  __shared__ __align__(16) char smem[NBUF * BUFB];

  const int tid = threadIdx.x;
  const int wave = tid >> 6, lane = tid & 63;  // wave 0..7
  const int bid = blockIdx.x;
  const int b = bid & 7;          // batch -> XCD
  const int bm = (bid >> 3) & 7;  // fastest: A streams, B-tile L2-hot
  const int bn = bid >> 6;

  const unsigned char* Ag = x1q + ((size_t)b * N1 + bm * BM) * KD;
  const unsigned char* Bg = x2q + ((size_t)b * N2 + bn * BN) * KD;

  // staging: lane -> (row lr, 16B slot sl), fetch the swizzled global group
  const int lr = lane >> 2, sl = lane & 3;
  const int goff = (sl ^ ((lr >> 1) & 3)) * 16;

  // fragments: lane (fr, quad) reads swizzled slot -> global 16B group `quad`
  const int quad = lane >> 4, fr = lane & 15;
  const int fslot = (fr * 4 + (quad ^ ((fr >> 1) & 3))) * 16;

  f32x4 acc[2][9];
#pragma unroll
  for (int i = 0; i < 2; ++i)
#pragma unroll
    for (int j = 0; j < 9; ++j) {
      f32x4 z = {0.f, 0.f, 0.f, 0.f};
      acc[i][j] = z;
    }

  // stage(k0): 25 chunks (0..15 = A 256 rows, 16..24 = B 144 rows).
  // UNIFORM 4 VMEM/wave: chunks 3w..3w+2 (waves 0..7 -> 0..23) + 24 by all.
  auto stage = [&](int buf, int k0) {
    char* base = smem + buf * BUFB;
#pragma unroll
    for (int t = 0; t < 3; ++t) {
      int j = wave * 3 + t;
      const unsigned char* g;
      if (j < 16)
        g = Ag + (size_t)(j * 16 + lr) * KD + k0 + goff;
      else
        g = Bg + (size_t)((j - 16) * 16 + lr) * KD + k0 + goff;
      async_copy16(g, base + j * 1024 + lane * 16);
    }
    // chunk 24 = B rows 128..143, staged redundantly by all 8 waves
    async_copy16(Bg + (size_t)(128 + lr) * KD + k0 + goff,
                 base + 24 * 1024 + lane * 16);
  };

#define COMPUTE(cbp)                                                          \
  {                                                                           \
    const char* cb = (cbp);                                                   \
    i64x2 a0 = *(const i64x2*)(cb + (2 * wave + 0) * 1024 + fslot);           \
    i64x2 a1 = *(const i64x2*)(cb + (2 * wave + 1) * 1024 + fslot);           \
    __builtin_amdgcn_s_setprio(1);                                            \
    _Pragma("unroll") for (int tn = 0; tn < 9; ++tn) {                        \
      i64x2 bf = *(const i64x2*)(cb + 16384 + tn * 1024 + fslot);             \
      acc[0][tn] = __builtin_amdgcn_mfma_f32_16x16x32_fp8_fp8(                \
          a0.x, bf.x, acc[0][tn], 0, 0, 0);                                   \
      acc[0][tn] = __builtin_amdgcn_mfma_f32_16x16x32_fp8_fp8(                \
          a0.y, bf.y, acc[0][tn], 0, 0, 0);                                   \
      acc[1][tn] = __builtin_amdgcn_mfma_f32_16x16x32_fp8_fp8(                \
          a1.x, bf.x, acc[1][tn], 0, 0, 0);                                   \
      acc[1][tn] = __builtin_amdgcn_mfma_f32_16x16x32_fp8_fp8(                \
          a1.y, bf.y, acc[1][tn], 0, 0, 0);                                   \
    }                                                                         \
    __builtin_amdgcn_s_setprio(0);                                            \
  }

  stage(0, 0);   // tiles 0,1 in flight (8 VMEM/wave)
  stage(1, 64);

  int cur = 0;
  for (int i = 0; i < 15; ++i) {
    // own prior ds_reads done + own stage(cur) done (in-order vmcnt), THEN
    // barrier => cross-wave: buf[cur] staged, overwrite target reader-free
    asm volatile("s_waitcnt lgkmcnt(0)" ::: "memory");
    asm volatile("s_waitcnt vmcnt(4)" ::: "memory");
    __builtin_amdgcn_s_barrier();
    __builtin_amdgcn_sched_barrier(0);
    if (i < 14) {
      int b2 = cur + 2;
      if (b2 >= NBUF) b2 -= NBUF;
      stage(b2, (i + 2) * 64);
    }
    COMPUTE(smem + cur * BUFB);
    ++cur;
    if (cur == NBUF) cur = 0;
  }
  // peeled last iter (tile 15): full drain allowed once
  asm volatile("s_waitcnt lgkmcnt(0)" ::: "memory");
  asm volatile("s_waitcnt vmcnt(0)" ::: "memory");
  __builtin_amdgcn_s_barrier();
  __builtin_amdgcn_sched_barrier(0);
  COMPUTE(smem + cur * BUFB);

  // ---- epilogue: d = sq1 + sq2 - 2*cross, min over 9-col groups, sum ----
  float s2[9];
#pragma unroll
  for (int tn = 0; tn < 9; ++tn)
    s2[tn] = sq2[(size_t)b * N2 + bn * BN + tn * 16 + fr];

  float s1v[2][4];
#pragma unroll
  for (int tm = 0; tm < 2; ++tm)
#pragma unroll
    for (int rr = 0; rr < 4; ++rr)
      s1v[tm][rr] =
          sq1[(size_t)b * N1 + bm * BM + (2 * wave + tm) * 16 + quad * 4 + rr];

  float* eps = (float*)smem;
  float local = 0.f;
#pragma unroll  // FULL unroll: acc indices must be compile-time constants
  for (int tm = 0; tm < 2; ++tm) {
    __syncthreads();  // K-loop LDS / previous pass fully consumed
    // D layout (16x16x32, dtype-independent): col = lane&15 (x2 row),
    // row = quad*4 + reg (x1 row within the 16-row A-chunk 2*wave+tm).
    // Pass tm writes 128 rows: row_local = wave*16 + quad*4 + rr.
#pragma unroll
    for (int tn = 0; tn < 9; ++tn)
#pragma unroll
      for (int rr = 0; rr < 4; ++rr)
        eps[(wave * 16 + quad * 4 + rr) * BNP + tn * 16 + fr] =
            s1v[tm][rr] + s2[tn] - 2.0f * acc[tm][tn][rr];
    __syncthreads();
    // 128 rows x 16 groups = 2048 groups, 4 per thread (512 threads)
#pragma unroll
    for (int qq = 0; qq < 4; ++qq) {
      int g = tid + qq * 512;
      int row = g >> 4, grp = g & 15;
      const float* p = eps + row * BNP + grp * 9;
      float mn = p[0];
#pragma unroll
      for (int jj = 1; jj < 9; ++jj) mn = fminf(mn, p[jj]);
      local += mn;
    }
  }

#pragma unroll
  for (int off = 32; off > 0; off >>= 1) local += __shfl_down(local, off);
  __syncthreads();
  if (lane == 0) eps[wave] = local;
  __syncthreads();
  if (tid == 0) {
    float s = 0.f;
#pragma unroll
    for (int w = 0; w < 8; ++w) s += eps[w];
    // total group count = 8 * 2048 * 1152 / 9 = 2097152
    atomicAdd(out, s * (1.0f / 2097152.0f));
  }
}

extern "C" void kernel_launch(void* const* d_in, const int* in_sizes, int n_in,
                              void* d_out, int out_size, void* d_ws, size_t ws_size,
                              hipStream_t stream) {
  const float* x1 = (const float*)d_in[0];
  const float* x2 = (const float*)d_in[1];
  char* ws = (char*)d_ws;
  const size_t x1q_bytes = (size_t)NB * N1 * KD;  // 16777216
  const size_t x2q_bytes = (size_t)NB * N2 * KD;  // 9437184
  unsigned char* x1q = (unsigned char*)ws;
  unsigned char* x2q = (unsigned char*)(ws + x1q_bytes);
  float* sq1 = (float*)(ws + x1q_bytes + x2q_bytes);
  float* sq2 = (float*)(ws + x1q_bytes + x2q_bytes + (size_t)NB * N1 * 4);

  convert_kernel<<<NB * (N1 / 4 + N2 / 4), 256, 0, stream>>>(x1, x2, x1q, x2q,
                                                             sq1, sq2,
                                                             (float*)d_out);
  dist_kernel<<<NB * (N1 / BM) * (N2 / BN), 512, 0, stream>>>(x1q, x2q, sq1, sq2,
                                                              (float*)d_out);
}

// Round 6
// 152.969 us; speedup vs baseline: 1.0517x; 1.0517x over previous
//
#include <hip/hip_runtime.h>

#define NB 8
#define N1 2048
#define N2 1152
#define KD 1024
#define BM 256
#define BN 144
#define BNP 145     // padded epilogue stride
#define BUFB 25600  // one staging buffer: 25 chunks x 1 KB (16 A + 9 B)
#define NBUF 3      // triple buffer -> counted vmcnt, no drain in loop (R3 +5us)

typedef __attribute__((ext_vector_type(4))) float f32x4;
typedef __attribute__((ext_vector_type(2))) long i64x2;

__device__ __forceinline__ unsigned pack4_fp8(f32x4 v) {
  int t = __builtin_amdgcn_cvt_pk_fp8_f32(v.x, v.y, 0, false);
  t = __builtin_amdgcn_cvt_pk_fp8_f32(v.z, v.w, t, true);
  return (unsigned)t;
}

__device__ __forceinline__ void async_copy16(const void* g, void* l) {
  __builtin_amdgcn_global_load_lds(
      (const __attribute__((address_space(1))) unsigned int*)g,
      (__attribute__((address_space(3))) unsigned int*)l, 16, 0, 0);
}

// convert: R4-verbatim (passed, absmax 0). ONE wave per row; wave-private LDS
// permute -> lgkmcnt(0) only, no block barrier. XCD-aligned: bid&7 = batch,
// fp8 writes stay hot in that XCD's 4 MB L2 for dist (R8-verified).
__global__ __launch_bounds__(256) void convert_kernel(
    const float* __restrict__ x1, const float* __restrict__ x2,
    unsigned char* __restrict__ x1q, unsigned char* __restrict__ x2q,
    float* __restrict__ sq1, float* __restrict__ sq2,
    float* __restrict__ out) {
  __shared__ __align__(16) unsigned char lds[4096];
  if (blockIdx.x == 0 && threadIdx.x == 0) *out = 0.f;  // replaces memset
  int wave = threadIdx.x >> 6, lane = threadIdx.x & 63;
  int bid = blockIdx.x;
  int b = bid & 7;          // batch -> XCD
  int idx = bid >> 3;       // 0..799 within batch
  const float* src;
  unsigned char* dst;
  float* sqp;
  if (idx < N1 / 4) {
    int row = b * N1 + idx * 4 + wave;
    src = x1 + (size_t)row * KD;
    dst = x1q + (size_t)row * KD;
    sqp = sq1 + row;
  } else {
    int row = b * N2 + (idx - N1 / 4) * 4 + wave;
    src = x2 + (size_t)row * KD;
    dst = x2q + (size_t)row * KD;
    sqp = sq2 + row;
  }
  const f32x4* s4 = (const f32x4*)src;
  int r = 4 * (lane & 15);
  int q = (r & 31) >> 3;
  int h = r >> 5;
  int pos = (lane >> 4) * 64 + q * 16 + h * 8 + (r & 7);
  unsigned char* my = lds + wave * 1024;
  float s = 0.f;
#pragma unroll
  for (int i = 0; i < 4; ++i) {
    f32x4 v = __builtin_nontemporal_load(&s4[i * 64 + lane]);
    *(unsigned*)(my + i * 256 + pos) = pack4_fp8(v);
    s += v.x * v.x + v.y * v.y + v.z * v.z + v.w * v.w;
  }
  // wave-private LDS, intra-wave lane exchange only: no block barrier needed
  asm volatile("s_waitcnt lgkmcnt(0)" ::: "memory");
  ((uint4*)dst)[lane] = *(const uint4*)(my + lane * 16);
#pragma unroll
  for (int off = 32; off > 0; off >>= 1) s += __shfl_down(s, off);
  if (lane == 0) *sqp = s;
}

// dist R15: REVERT to R3's 4-wave/256-thr geometry (R5's 8-wave spilled:
// WRITE_SIZE 7.2 MB scratch at the 128-reg cap -> 42us vs R3's ~31.8us).
// Tribuf + counted vmcnt kept (R3-proven, absmax 0). Two VGPR-neutral fixes:
//  (1) critical-path reorder: post-barrier, the 5 fragment ds_read_b128s
//      issue BEFORE the stage block, so stage's ~35 addr-VALU instrs overlap
//      ds_read latency instead of preceding it (R5 diagnosis: serial head).
//  (2) epilogue merged to 2 passes (eps = 128 rows x 145 f32 = 74.2 KB <=
//      76.8 KB) -> 4 syncthreads instead of 8.
// setprio DROPPED (R4: null, catalog-consistent on lockstep schedules).
// Sync skeleton (R3-proven): per-iter lgkmcnt(0)+vmcnt(7) BEFORE s_barrier
// => after barrier buf[cur] fully staged by all waves and buf[cur+2]
// (overwritten next) has no pending readers; 2 full compute phases of load
// slack; last iter peeled with vmcnt(0). Staging UNIFORM 7 loads/wave.
// CRITICAL: every loop touching acc[][] FULLY UNROLLED (runtime index =
// scratch; tripwire: dist WRITE_SIZE must stay ~0 — R5's was 7.2 MB).
// Grid 512: b = bid&7 -> batch b on XCD b (fp8 L2-hot from convert).
// LDS chunks 1 KB = 16 rows x 64 fp8, XOR swizzle (slot ^ (row>>1)&3) ->
// conflict-free b128 fragment reads (verified R2-R9).
__global__ __launch_bounds__(256, 2) void dist_kernel(
    const unsigned char* __restrict__ x1q, const unsigned char* __restrict__ x2q,
    const float* __restrict__ sq1, const float* __restrict__ sq2,
    float* __restrict__ out) {
  __shared__ __align__(16) char smem[NBUF * BUFB];

  const int tid = threadIdx.x;
  const int wave = tid >> 6, lane = tid & 63;
  const int bid = blockIdx.x;
  const int b = bid & 7;          // batch -> XCD
  const int bm = (bid >> 3) & 7;  // fastest: A streams, B-tile L2-hot
  const int bn = bid >> 6;

  const unsigned char* Ag = x1q + ((size_t)b * N1 + bm * BM) * KD;
  const unsigned char* Bg = x2q + ((size_t)b * N2 + bn * BN) * KD;

  // staging: lane -> (row lr, 16B slot sl), fetch the swizzled global group
  const int lr = lane >> 2, sl = lane & 3;
  const int goff = (sl ^ ((lr >> 1) & 3)) * 16;

  // fragments: lane (fr, quad) reads swizzled slot -> global 16B group `quad`
  const int quad = lane >> 4, fr = lane & 15;
  const int fslot = (fr * 4 + (quad ^ ((fr >> 1) & 3))) * 16;

  f32x4 acc[4][9];
#pragma unroll
  for (int i = 0; i < 4; ++i)
#pragma unroll
    for (int j = 0; j < 9; ++j) {
      f32x4 z = {0.f, 0.f, 0.f, 0.f};
      acc[i][j] = z;
    }

  // stage(k0) into buffer `buf`: 25 chunks (0..15 = A 256 rows, 16..24 = B
  // 144). UNIFORM 7 VMEM/wave: chunks 6w..6w+5 per wave + chunk 24 by all.
  auto stage = [&](int buf, int k0) {
    char* base = smem + buf * BUFB;
#pragma unroll
    for (int t = 0; t < 6; ++t) {
      int j = wave * 6 + t;
      const unsigned char* g;
      if (j < 16)
        g = Ag + (size_t)(j * 16 + lr) * KD + k0 + goff;
      else
        g = Bg + (size_t)((j - 16) * 16 + lr) * KD + k0 + goff;
      async_copy16(g, base + j * 1024 + lane * 16);
    }
    // chunk 24 = B rows 128..143, staged redundantly by all 4 waves
    async_copy16(Bg + (size_t)(128 + lr) * KD + k0 + goff,
                 base + 24 * 1024 + lane * 16);
  };

#define MFMA8(tn)                                                             \
  acc[0][tn] = __builtin_amdgcn_mfma_f32_16x16x32_fp8_fp8(a0.x, bf.x,         \
                                                          acc[0][tn], 0, 0, 0); \
  acc[0][tn] = __builtin_amdgcn_mfma_f32_16x16x32_fp8_fp8(a0.y, bf.y,         \
                                                          acc[0][tn], 0, 0, 0); \
  acc[1][tn] = __builtin_amdgcn_mfma_f32_16x16x32_fp8_fp8(a1.x, bf.x,         \
                                                          acc[1][tn], 0, 0, 0); \
  acc[1][tn] = __builtin_amdgcn_mfma_f32_16x16x32_fp8_fp8(a1.y, bf.y,         \
                                                          acc[1][tn], 0, 0, 0); \
  acc[2][tn] = __builtin_amdgcn_mfma_f32_16x16x32_fp8_fp8(a2.x, bf.x,         \
                                                          acc[2][tn], 0, 0, 0); \
  acc[2][tn] = __builtin_amdgcn_mfma_f32_16x16x32_fp8_fp8(a2.y, bf.y,         \
                                                          acc[2][tn], 0, 0, 0); \
  acc[3][tn] = __builtin_amdgcn_mfma_f32_16x16x32_fp8_fp8(a3.x, bf.x,         \
                                                          acc[3][tn], 0, 0, 0); \
  acc[3][tn] = __builtin_amdgcn_mfma_f32_16x16x32_fp8_fp8(a3.y, bf.y,         \
                                                          acc[3][tn], 0, 0, 0);

// K-body: fragment ds_reads FIRST (critical path), stage overlaps their
// latency, then MFMAs (tn=0 peeled; tn>=1 reads interleave as before).
#define KBODY(cbp, do_stage, knext)                                           \
  {                                                                           \
    const char* cb = (cbp);                                                   \
    i64x2 a0 = *(const i64x2*)(cb + (wave * 4 + 0) * 1024 + fslot);           \
    i64x2 a1 = *(const i64x2*)(cb + (wave * 4 + 1) * 1024 + fslot);           \
    i64x2 a2 = *(const i64x2*)(cb + (wave * 4 + 2) * 1024 + fslot);           \
    i64x2 a3 = *(const i64x2*)(cb + (wave * 4 + 3) * 1024 + fslot);           \
    i64x2 bf = *(const i64x2*)(cb + 16384 + fslot);                           \
    if (do_stage) {                                                           \
      int b2 = cur + 2;                                                       \
      if (b2 >= NBUF) b2 -= NBUF;                                             \
      stage(b2, (knext)*64);                                                  \
    }                                                                         \
    MFMA8(0)                                                                  \
    _Pragma("unroll") for (int tn = 1; tn < 9; ++tn) {                        \
      bf = *(const i64x2*)(cb + 16384 + tn * 1024 + fslot);                   \
      MFMA8(tn)                                                               \
    }                                                                         \
  }

  stage(0, 0);   // tiles 0,1 in flight (14 VMEM/wave)
  stage(1, 64);

  int cur = 0;
  for (int i = 0; i < 15; ++i) {
    // own prior ds_reads done + own stage(cur) done (in-order vmcnt), THEN
    // barrier => cross-wave: buf[cur] staged, overwrite target reader-free
    asm volatile("s_waitcnt lgkmcnt(0)" ::: "memory");
    asm volatile("s_waitcnt vmcnt(7)" ::: "memory");
    __builtin_amdgcn_s_barrier();
    __builtin_amdgcn_sched_barrier(0);
    KBODY(smem + cur * BUFB, (i < 14), i + 2);
    ++cur;
    if (cur == NBUF) cur = 0;
  }
  // peeled last iter (tile 15, buffer 0): full drain allowed once
  asm volatile("s_waitcnt lgkmcnt(0)" ::: "memory");
  asm volatile("s_waitcnt vmcnt(0)" ::: "memory");
  __builtin_amdgcn_s_barrier();
  __builtin_amdgcn_sched_barrier(0);
  KBODY(smem + cur * BUFB, false, 0);

  // ---- epilogue: d = sq1 + sq2 - 2*cross, min over 9-col groups, sum ----
  // Merged 2-pass: eps holds 128 rows x BNP (74240 B <= 76800 LDS) ->
  // 2 tm-chunks per pass, 4 syncthreads total (was 8).
  float s2[9];
#pragma unroll
  for (int tn = 0; tn < 9; ++tn)
    s2[tn] = sq2[(size_t)b * N2 + bn * BN + tn * 16 + fr];

  float s1v[4][4];
#pragma unroll
  for (int tm = 0; tm < 4; ++tm)
#pragma unroll
    for (int rr = 0; rr < 4; ++rr)
      s1v[tm][rr] = sq1[(size_t)b * N1 + bm * BM + wave * 64 + tm * 16 + quad * 4 + rr];

  float* eps = (float*)smem;
  float local = 0.f;
#pragma unroll  // FULL unroll: acc indices must be compile-time constants
  for (int p = 0; p < 2; ++p) {
    __syncthreads();  // K-loop LDS / previous pass fully consumed
    // D layout (16x16x32, dtype-independent): col = lane&15 (x2 row),
    // row = quad*4 + reg (x1 row). Pass p covers tm = 2p..2p+1 ->
    // 128 eps rows: row_local = h*64 + wave*16 + quad*4 + rr.
#pragma unroll
    for (int h = 0; h < 2; ++h)
#pragma unroll
      for (int tn = 0; tn < 9; ++tn)
#pragma unroll
        for (int rr = 0; rr < 4; ++rr)
          eps[(h * 64 + wave * 16 + quad * 4 + rr) * BNP + tn * 16 + fr] =
              s1v[2 * p + h][rr] + s2[tn] - 2.0f * acc[2 * p + h][tn][rr];
    __syncthreads();
    // 128 rows x 16 groups = 2048 groups, 8 per thread (256 threads)
#pragma unroll
    for (int qq = 0; qq < 8; ++qq) {
      int g = tid + qq * 256;
      int row = g >> 4, grp = g & 15;
      const float* pp = eps + row * BNP + grp * 9;
      float mn = pp[0];
#pragma unroll
      for (int jj = 1; jj < 9; ++jj) mn = fminf(mn, pp[jj]);
      local += mn;
    }
  }

#pragma unroll
  for (int off = 32; off > 0; off >>= 1) local += __shfl_down(local, off);
  __syncthreads();
  if (lane == 0) eps[wave] = local;
  __syncthreads();
  if (tid == 0) {
    float s = eps[0] + eps[1] + eps[2] + eps[3];
    // total group count = 8 * 2048 * 1152 / 9 = 2097152
    atomicAdd(out, s * (1.0f / 2097152.0f));
  }
}

extern "C" void kernel_launch(void* const* d_in, const int* in_sizes, int n_in,
                              void* d_out, int out_size, void* d_ws, size_t ws_size,
                              hipStream_t stream) {
  const float* x1 = (const float*)d_in[0];
  const float* x2 = (const float*)d_in[1];
  char* ws = (char*)d_ws;
  const size_t x1q_bytes = (size_t)NB * N1 * KD;  // 16777216
  const size_t x2q_bytes = (size_t)NB * N2 * KD;  // 9437184
  unsigned char* x1q = (unsigned char*)ws;
  unsigned char* x2q = (unsigned char*)(ws + x1q_bytes);
  float* sq1 = (float*)(ws + x1q_bytes + x2q_bytes);
  float* sq2 = (float*)(ws + x1q_bytes + x2q_bytes + (size_t)NB * N1 * 4);

  convert_kernel<<<NB * (N1 / 4 + N2 / 4), 256, 0, stream>>>(x1, x2, x1q, x2q,
                                                             sq1, sq2,
                                                             (float*)d_out);
  dist_kernel<<<NB * (N1 / BM) * (N2 / BN), 256, 0, stream>>>(x1q, x2q, sq1, sq2,
                                                              (float*)d_out);
}